// Round 10
// baseline (1880.496 us; speedup 1.0000x reference)
//
#include <hip/hip_runtime.h>
#include <hip/hip_cooperative_groups.h>

namespace cg = cooperative_groups;

#define DT 0.001f
#define GAMMA 2.0f

#define KSTEPS 60         // steps per phase (last phase: 40; both %4==0)
#define HALOB  120        // block halo = 2*KSTEPS (radius 2 nodes/step)
#define TILE   144        // interior nodes per block -> 228 blocks (<= 256 CUs)
#define REGION 384        // TILE + 2*HALOB = NW*WINT
#define NW     8          // waves per block (512 thr -> 2 waves/SIMD)
#define WINT   48         // wave-interior lanes (1 node each)
#define WHALO  8          // wave halo lanes per side = 2*JEXCH
#define JEXCH  4          // steps between intra-block LDS exchanges
#define NTHREADS 512

typedef float v2f __attribute__((ext_vector_type(2)));

// LDS-only barrier (global trajectory stores stay in flight).
__device__ __forceinline__ void lds_barrier() {
    asm volatile("s_waitcnt lgkmcnt(0)" ::: "memory");
    __builtin_amdgcn_s_barrier();
    asm volatile("" ::: "memory");
}

// DPP wave-wide shifts (bound_ctrl: OOB lanes get 0 -> lands only in trapezoid halo)
__device__ __forceinline__ float dpp_shl1(float x) {   // lane i <- lane i+1
    return __int_as_float(__builtin_amdgcn_update_dpp(
        0, __float_as_int(x), 0x130, 0xF, 0xF, true));
}
__device__ __forceinline__ float dpp_shr1(float x) {   // lane i <- lane i-1
    return __int_as_float(__builtin_amdgcn_update_dpp(
        0, __float_as_int(x), 0x138, 0xF, 0xF, true));
}

// Single cooperative launch: 17 phases of <=60 steps, grid.sync() between
// phases (replaces 17 kernel launches + init kernel). Per-step math, LDS
// exchange, and store batching identical to previous round (bit-identical).
__global__ __launch_bounds__(NTHREADS) void sim_kernel(
    const float* __restrict__ init_pos,
    const int*   __restrict__ buckle,      // (H,4) int32
    const float* __restrict__ thetas_ss,   // (H,)
    const float* __restrict__ rest_len,    // (H+1,)
    const float* __restrict__ kstiff_p,
    const float* __restrict__ ksoft_p,
    const float* __restrict__ kstretch_p,
    float* __restrict__ out,
    float* __restrict__ sAx, float* __restrict__ sAv,
    float* __restrict__ sBx, float* __restrict__ sBv,
    int N, int H, int n_coords, int n_steps)
{
    __shared__ float4 xch[2][REGION];      // double-buffered pos+vel exchange

    cg::grid_group grid = cg::this_grid();

    const int lane = threadIdx.x & 63;
    const int w    = threadIdx.x >> 6;
    const int r    = w * WINT + lane - WHALO;           // region node (may be OOB)
    const int tile_start = blockIdx.x * TILE;
    const int jg   = tile_start - HALOB + r;            // global node
    const bool rvalid = (r >= 0) && (r < REGION);
    const bool nvalid = (jg >= 0) && (jg < N);
    const int  jc   = min(max(jg, 0), N - 1);           // clamped load index

    const float kS  = kstiff_p[0];
    const float kw  = ksoft_p[0];
    const float kst = kstretch_p[0];

    const bool edge_ok  = (jg >= 0) && (jg <= N - 2);
    const bool hinge_ok = (jg >= 0) && (jg < H);

    // hoisted per-lane constants with validity folded in (NaN-safe)
    const float rl     = rest_len[min(max(jg, 0), H)];
    const float emask  = edge_ok ? 1.0f : 0.0f;
    const float efix   = edge_ok ? 0.0f : 1.0f;   // l2 guard: keeps rsq finite
    const float kst_l  = edge_ok ? kst : 0.0f;
    const float kstrl  = kst * rl;
    const float hfix   = hinge_ok ? 0.0f : 1.0f;  // dd guard: keeps rcp finite
    float tss = 0.0f, npf = 0.0f;
    if (hinge_ok) {
        tss = thetas_ss[jg];
        int4 b = reinterpret_cast<const int4*>(buckle)[jg];
        npf = (float)((b.x == 1) + (b.y == 1) + (b.z == 1) + (b.w == 1));
    }
    const float ntss  = -tss;
    const float npf4m = 4.0f - npf;
    const float dKl   = hinge_ok ? (kS - kw) : 0.0f;   // K = fma(ns,dKl,kw4l)
    const float kw4l  = hinge_ok ? 4.0f * kw : 0.0f;   // -> 0 for non-hinge lanes

    const bool pinned = nvalid && (jg < 2);
    v2f pin = {0.0f, 0.0f};
    if (pinned) { pin.x = init_pos[2 * jg]; pin.y = init_pos[2 * jg + 1]; }

    const bool wave_int = (lane >= WHALO) && (lane < WHALO + WINT);
    const bool writer   = wave_int && (r >= HALOB) && (r < HALOB + TILE) && nvalid;

    const size_t tstride = (size_t)(n_coords / 2);   // float2 elements per row
    const float C998 = 1.0f - GAMMA * DT;

    int phase = 0;
    for (int t0 = 0; t0 < n_steps; t0 += KSTEPS, ++phase) {
        const int ksteps = min(KSTEPS, n_steps - t0);

        // load phase-start state (phase 0: initial conditions)
        v2f p, v;
        if (phase == 0) {
            float2 P0 = reinterpret_cast<const float2*>(init_pos)[jc];
            p.x = P0.x; p.y = P0.y;
            v.x = 0.0f; v.y = 0.0f;
        } else {
            const float* xr = (phase & 1) ? sAx : sBx;   // previous phase's write buf
            const float* vr = (phase & 1) ? sAv : sBv;
            float2 P0 = reinterpret_cast<const float2*>(xr)[jc];
            float2 V0 = reinterpret_cast<const float2*>(vr)[jc];
            p.x = P0.x; p.y = P0.y;
            v.x = V0.x; v.y = V0.y;
        }

        float2* tptr = reinterpret_cast<float2*>(out + (size_t)(t0 + 1) * (size_t)n_coords) + jc;

        for (int s0 = 0; s0 < ksteps; s0 += JEXCH) {
            if (s0 > 0) {
                int buf = (s0 >> 2) & 1;
                if (wave_int && rvalid) xch[buf][r] = make_float4(p.x, p.y, v.x, v.y);
                lds_barrier();
                if (rvalid) {
                    float4 f4 = xch[buf][r];
                    p.x = f4.x; p.y = f4.y; v.x = f4.z; v.y = f4.w;
                }
            }
            float2 sbuf[JEXCH];                // group-local trajectory buffer (regs)
            #pragma unroll
            for (int u = 0; u < JEXCH; ++u) {
                // p_{j+1}, edge j, edge j+1 (shift the edge, not the far point)
                v2f q;  q.x  = dpp_shl1(p.x); q.y  = dpp_shl1(p.y);
                v2f e  = q - p;
                v2f en; en.x = dpp_shl1(e.x); en.y = dpp_shl1(e.y);

                float l2   = fmaf(e.x, e.x, fmaf(e.y, e.y, efix));
                float irt  = __builtin_amdgcn_rsqf(l2) * emask;  // masked 1/len
                float il2  = irt * irt;
                float se   = fmaf(-kstrl, irt, kst_l);           // kst*(len-rl)/len

                float cr = e.x * en.y - e.y * en.x;
                float dd = fmaf(e.x, en.x, fmaf(e.y, en.y, hfix));
                // small-angle atan2 (|theta| < 0.3 always; dd ~ 1 > 0)
                float t  = cr * __builtin_amdgcn_rcpf(dd);
                float t2 = t * t;
                float pp = -0.0040540580f;
                pp = fmaf(pp, t2,  0.0218612288f);
                pp = fmaf(pp, t2, -0.0559098861f);
                pp = fmaf(pp, t2,  0.0964200441f);
                pp = fmaf(pp, t2, -0.1390853351f);
                pp = fmaf(pp, t2,  0.1994653599f);
                pp = fmaf(pp, t2, -0.3332985605f);
                pp = fmaf(pp, t2,  0.9999993329f);
                float th   = pp * t;
                float thmt = th - tss;
                float ns = (th > ntss ? npf : 0.0f) + (th < tss ? npf4m : 0.0f);
                float K  = fmaf(ns, dKl, kw4l);
                float g  = K * thmt;

                float gm   = dpp_shr1(g);
                float coef = (gm - g) * il2;
                v2f F;
                F.x = fmaf(coef, -e.y, se * e.x);
                F.y = fmaf(coef,  e.x, se * e.y);
                v2f Fp; Fp.x = dpp_shr1(F.x); Fp.y = dpp_shr1(F.y);

                v2f f = F - Fp;
                v = v * C998 + f * DT;
                p = p + v * DT;
                if (tile_start == 0) {                            // uniform guard
                    if (pinned) { v.x = 0.0f; v.y = 0.0f; p = pin; }
                }
                sbuf[u] = make_float2(p.x, p.y);
            }
            // issue the group's stores together; drain under subsequent compute
            if (writer) {
                #pragma unroll
                for (int u = 0; u < JEXCH; ++u) {
                    tptr[(size_t)u * tstride] = sbuf[u];
                }
            }
            tptr += (size_t)JEXCH * tstride;
        }

        // write phase-end state for the next phase
        float* xw = (phase & 1) ? sBx : sAx;
        float* vw = (phase & 1) ? sBv : sAv;
        if (writer) {
            reinterpret_cast<float2*>(xw)[jg] = make_float2(p.x, p.y);
            reinterpret_cast<float2*>(vw)[jg] = make_float2(v.x, v.y);
            if (t0 + ksteps == n_steps) {
                reinterpret_cast<float2*>(out)[jg] = make_float2(p.x, p.y);  // x_final
            }
        }
        __threadfence();   // release: make state visible across XCDs
        grid.sync();
        __threadfence();   // acquire side
    }
}

extern "C" void kernel_launch(void* const* d_in, const int* in_sizes, int n_in,
                              void* d_out, int out_size, void* d_ws, size_t ws_size,
                              hipStream_t stream) {
    const float* init_pos  = (const float*)d_in[0];
    const int*   buckle    = (const int*)d_in[1];
    const float* thetas_ss = (const float*)d_in[2];
    const float* rest_len  = (const float*)d_in[3];
    const float* kstiff    = (const float*)d_in[4];
    const float* ksoft     = (const float*)d_in[5];
    const float* kstretch  = (const float*)d_in[6];

    const int n_coords = in_sizes[0];             // 65540
    int N = n_coords / 2;                         // 32770 nodes
    int H = in_sizes[2];                          // 32768 hinges
    int n_steps = out_size / n_coords - 1;        // 1000
    int nc = n_coords;

    float* out = (float*)d_out;
    float* wsf = (float*)d_ws;
    float* sAx = wsf;
    float* sAv = wsf + n_coords;
    float* sBx = wsf + 2 * n_coords;
    float* sBv = wsf + 3 * n_coords;

    const int nblocks = (N + TILE - 1) / TILE;    // 228

    void* args[] = {
        (void*)&init_pos, (void*)&buckle, (void*)&thetas_ss, (void*)&rest_len,
        (void*)&kstiff, (void*)&ksoft, (void*)&kstretch,
        (void*)&out, (void*)&sAx, (void*)&sAv, (void*)&sBx, (void*)&sBv,
        (void*)&N, (void*)&H, (void*)&nc, (void*)&n_steps
    };
    hipLaunchCooperativeKernel((const void*)sim_kernel,
                               dim3(nblocks), dim3(NTHREADS),
                               args, 0, stream);
}

// Round 13
// 393.736 us; speedup vs baseline: 4.7760x; 4.7760x over previous
//
#include <hip/hip_runtime.h>

#define DT 0.001f
#define GAMMA 2.0f

#define KSTEPS 60         // steps per phase (last phase: 40; both %4==0)
#define HALOB  120        // block halo = 2*KSTEPS (radius 2 nodes/step)
#define TILE   144        // interior nodes per block -> 228 blocks (<= 256 CUs)
#define REGION 384        // TILE + 2*HALOB = NW*WINT
#define NW     8          // waves per block (512 thr -> 2 waves/SIMD)
#define WINT   48         // wave-interior lanes (1 node each)
#define WHALO  8          // wave halo lanes per side = 2*JEXCH
#define JEXCH  4          // steps between intra-block LDS exchanges
#define NTHREADS 512

typedef float v2f __attribute__((ext_vector_type(2)));

// LDS-only barrier (global trajectory stores stay in flight).
__device__ __forceinline__ void lds_barrier() {
    asm volatile("s_waitcnt lgkmcnt(0)" ::: "memory");
    __builtin_amdgcn_s_barrier();
    asm volatile("" ::: "memory");
}

// DPP wave-wide shifts (bound_ctrl: OOB lanes get 0 -> lands only in trapezoid halo)
__device__ __forceinline__ float dpp_shl1(float x) {   // lane i <- lane i+1
    return __int_as_float(__builtin_amdgcn_update_dpp(
        0, __float_as_int(x), 0x130, 0xF, 0xF, true));
}
__device__ __forceinline__ float dpp_shr1(float x) {   // lane i <- lane i-1
    return __int_as_float(__builtin_amdgcn_update_dpp(
        0, __float_as_int(x), 0x138, 0xF, 0xF, true));
}

__device__ __forceinline__ unsigned long long pack2(float a, float b) {
    union { float f[2]; unsigned long long u; } c; c.f[0] = a; c.f[1] = b; return c.u;
}
__device__ __forceinline__ v2f unpack2(unsigned long long u) {
    union { float f[2]; unsigned long long u2; } c; c.u2 = u;
    v2f r; r.x = c.f[0]; r.y = c.f[1]; return r;
}

// Persistent kernel, one launch. Phase boundary protocol (fixed ordering):
//   publish (p,v) as agent-scope atomic stores
//   -> per-thread s_waitcnt vmcnt(0)   [every thread's stores COMPLETE]
//   -> __syncthreads()                  [no thread passes until all complete]
//   -> tid0: RELEASE-store flags[b]=ph+1; tid0/tid64 ACQUIRE-spin on flags[b-/+1]
//   -> __syncthreads()
//   -> halo lanes reload neighbor state (relaxed agent loads; ordered by the
//      acquire + barrier chain, fresh by scope)
// Interior lanes keep (p,v) in registers across phases. Per-step math
// bit-identical to the proven 17-launch version.
__global__ __launch_bounds__(NTHREADS) void sim_kernel(
    const float* __restrict__ init_pos,
    const int*   __restrict__ buckle,      // (H,4) int32
    const float* __restrict__ thetas_ss,   // (H,)
    const float* __restrict__ rest_len,    // (H+1,)
    const float* __restrict__ kstiff_p,
    const float* __restrict__ ksoft_p,
    const float* __restrict__ kstretch_p,
    float* __restrict__ out,
    float4* __restrict__ stA, float4* __restrict__ stB,
    int* __restrict__ flags,
    int N, int H, int n_coords, int n_steps)
{
    __shared__ float4 xch[2][REGION];      // double-buffered intra-phase exchange

    const int lane = threadIdx.x & 63;
    const int w    = threadIdx.x >> 6;
    const int r    = w * WINT + lane - WHALO;           // region node (may be OOB)
    const int b    = blockIdx.x;
    const int tile_start = b * TILE;
    const int jg   = tile_start - HALOB + r;            // global node
    const bool rvalid = (r >= 0) && (r < REGION);
    const bool nvalid = (jg >= 0) && (jg < N);
    const int  jc   = min(max(jg, 0), N - 1);           // clamped load index

    const float kS  = kstiff_p[0];
    const float kw  = ksoft_p[0];
    const float kst = kstretch_p[0];

    const bool edge_ok  = (jg >= 0) && (jg <= N - 2);
    const bool hinge_ok = (jg >= 0) && (jg < H);

    // hoisted per-lane constants with validity folded in (NaN-safe)
    const float rl     = rest_len[min(max(jg, 0), H)];
    const float emask  = edge_ok ? 1.0f : 0.0f;
    const float efix   = edge_ok ? 0.0f : 1.0f;   // l2 guard: keeps rsq finite
    const float kst_l  = edge_ok ? kst : 0.0f;
    const float kstrl  = kst * rl;
    const float hfix   = hinge_ok ? 0.0f : 1.0f;  // dd guard: keeps rcp finite
    float tss = 0.0f, npf = 0.0f;
    if (hinge_ok) {
        tss = thetas_ss[jg];
        int4 bk = reinterpret_cast<const int4*>(buckle)[jg];
        npf = (float)((bk.x == 1) + (bk.y == 1) + (bk.z == 1) + (bk.w == 1));
    }
    const float ntss  = -tss;
    const float npf4m = 4.0f - npf;
    const float dKl   = hinge_ok ? (kS - kw) : 0.0f;   // K = fma(ns,dKl,kw4l)
    const float kw4l  = hinge_ok ? 4.0f * kw : 0.0f;

    const bool pinned = nvalid && (jg < 2);
    v2f pin = {0.0f, 0.0f};
    if (pinned) { pin.x = init_pos[2 * jg]; pin.y = init_pos[2 * jg + 1]; }

    const bool wave_int = (lane >= WHALO) && (lane < WHALO + WINT);
    const bool writer   = wave_int && (r >= HALOB) && (r < HALOB + TILE) && nvalid;

    const size_t tstride = (size_t)(n_coords / 2);   // float2 elements per row
    const float C998 = 1.0f - GAMMA * DT;
    const int nphases = (n_steps + KSTEPS - 1) / KSTEPS;

    // phase-0 state: initial conditions (replaces the old init kernel)
    float2 P0 = reinterpret_cast<const float2*>(init_pos)[jc];
    v2f p = {P0.x, P0.y};
    v2f v = {0.0f, 0.0f};

    for (int ph = 0; ph < nphases; ++ph) {
        const int t0 = ph * KSTEPS;
        const int ksteps = min(KSTEPS, n_steps - t0);

        float2* tptr = reinterpret_cast<float2*>(out + (size_t)(t0 + 1) * (size_t)n_coords) + jc;

        for (int s0 = 0; s0 < ksteps; s0 += JEXCH) {
            if (s0 > 0) {
                int buf = (s0 >> 2) & 1;
                if (wave_int && rvalid) xch[buf][r] = make_float4(p.x, p.y, v.x, v.y);
                lds_barrier();
                if (rvalid) {
                    float4 f4 = xch[buf][r];
                    p.x = f4.x; p.y = f4.y; v.x = f4.z; v.y = f4.w;
                }
            }
            float2 sbuf[JEXCH];                // group-local trajectory buffer (regs)
            #pragma unroll
            for (int u = 0; u < JEXCH; ++u) {
                v2f q;  q.x  = dpp_shl1(p.x); q.y  = dpp_shl1(p.y);
                v2f e  = q - p;
                v2f en; en.x = dpp_shl1(e.x); en.y = dpp_shl1(e.y);

                float l2   = fmaf(e.x, e.x, fmaf(e.y, e.y, efix));
                float irt  = __builtin_amdgcn_rsqf(l2) * emask;  // masked 1/len
                float il2  = irt * irt;
                float se   = fmaf(-kstrl, irt, kst_l);           // kst*(len-rl)/len

                float cr = e.x * en.y - e.y * en.x;
                float dd = fmaf(e.x, en.x, fmaf(e.y, en.y, hfix));
                // small-angle atan2 (|theta| < 0.3 always; dd ~ 1 > 0)
                float t  = cr * __builtin_amdgcn_rcpf(dd);
                float t2 = t * t;
                float pp = -0.0040540580f;
                pp = fmaf(pp, t2,  0.0218612288f);
                pp = fmaf(pp, t2, -0.0559098861f);
                pp = fmaf(pp, t2,  0.0964200441f);
                pp = fmaf(pp, t2, -0.1390853351f);
                pp = fmaf(pp, t2,  0.1994653599f);
                pp = fmaf(pp, t2, -0.3332985605f);
                pp = fmaf(pp, t2,  0.9999993329f);
                float th   = pp * t;
                float thmt = th - tss;
                float ns = (th > ntss ? npf : 0.0f) + (th < tss ? npf4m : 0.0f);
                float K  = fmaf(ns, dKl, kw4l);
                float g  = K * thmt;

                float gm   = dpp_shr1(g);
                float coef = (gm - g) * il2;
                v2f F;
                F.x = fmaf(coef, -e.y, se * e.x);
                F.y = fmaf(coef,  e.x, se * e.y);
                v2f Fp; Fp.x = dpp_shr1(F.x); Fp.y = dpp_shr1(F.y);

                v2f f = F - Fp;
                v = v * C998 + f * DT;
                p = p + v * DT;
                if (tile_start == 0) {                            // uniform guard
                    if (pinned) { v.x = 0.0f; v.y = 0.0f; p = pin; }
                }
                sbuf[u] = make_float2(p.x, p.y);
            }
            if (writer) {
                #pragma unroll
                for (int u = 0; u < JEXCH; ++u) {
                    tptr[(size_t)u * tstride] = sbuf[u];
                }
            }
            tptr += (size_t)JEXCH * tstride;
        }

        if (t0 + ksteps == n_steps) {
            if (writer) {
                reinterpret_cast<float2*>(out)[jg] = make_float2(p.x, p.y);  // x_final
            }
            break;   // last phase: no publish/sync needed
        }

        // ---- publish phase-end state (agent-scope atomics; parity ph&1) ----
        float4* st = (ph & 1) ? stB : stA;
        if (writer) {
            unsigned long long* dst = reinterpret_cast<unsigned long long*>(&st[jg]);
            __hip_atomic_store(dst + 0, pack2(p.x, p.y),
                               __ATOMIC_RELAXED, __HIP_MEMORY_SCOPE_AGENT);
            __hip_atomic_store(dst + 1, pack2(v.x, v.y),
                               __ATOMIC_RELAXED, __HIP_MEMORY_SCOPE_AGENT);
        }
        // EVERY thread completes its publish stores before anyone passes the
        // barrier (workgroup barrier alone does not order agent-scope stores,
        // and thread0's release would only cover thread0's own stores).
        asm volatile("s_waitcnt vmcnt(0)" ::: "memory");
        __syncthreads();
        if (threadIdx.x == 0) {
            __hip_atomic_store(&flags[b], ph + 1,
                               __ATOMIC_RELEASE, __HIP_MEMORY_SCOPE_AGENT);
            if (b > 0) {
                while (__hip_atomic_load(&flags[b - 1], __ATOMIC_ACQUIRE,
                                         __HIP_MEMORY_SCOPE_AGENT) < ph + 1)
                    __builtin_amdgcn_s_sleep(2);
            }
        }
        if (threadIdx.x == 64 && b + 1 < (int)gridDim.x) {
            while (__hip_atomic_load(&flags[b + 1], __ATOMIC_ACQUIRE,
                                     __HIP_MEMORY_SCOPE_AGENT) < ph + 1)
                __builtin_amdgcn_s_sleep(2);
        }
        __syncthreads();   // spin completion visible to all threads

        // ---- halo refresh: non-writers reload published state; writers keep regs ----
        if (!writer) {
            const unsigned long long* src = reinterpret_cast<const unsigned long long*>(&st[jc]);
            unsigned long long up = __hip_atomic_load(src + 0, __ATOMIC_RELAXED,
                                                      __HIP_MEMORY_SCOPE_AGENT);
            unsigned long long uv = __hip_atomic_load(src + 1, __ATOMIC_RELAXED,
                                                      __HIP_MEMORY_SCOPE_AGENT);
            p = unpack2(up);
            v = unpack2(uv);
        }
    }
}

extern "C" void kernel_launch(void* const* d_in, const int* in_sizes, int n_in,
                              void* d_out, int out_size, void* d_ws, size_t ws_size,
                              hipStream_t stream) {
    const float* init_pos  = (const float*)d_in[0];
    const int*   buckle    = (const int*)d_in[1];
    const float* thetas_ss = (const float*)d_in[2];
    const float* rest_len  = (const float*)d_in[3];
    const float* kstiff    = (const float*)d_in[4];
    const float* ksoft     = (const float*)d_in[5];
    const float* kstretch  = (const float*)d_in[6];

    const int n_coords = in_sizes[0];             // 65540
    const int N = n_coords / 2;                   // 32770 nodes
    const int H = in_sizes[2];                    // 32768 hinges
    const int n_steps = out_size / n_coords - 1;  // 1000

    float* out = (float*)d_out;
    float4* stA = (float4*)d_ws;                  // N float4 (p,v) parity 0
    float4* stB = stA + N;                        // N float4 parity 1
    int* flags  = (int*)(stB + N);                // nblocks ints

    const int nblocks = (N + TILE - 1) / TILE;    // 228

    // reset neighbor-sync flags each call (capture-legal async memset)
    (void)hipMemsetAsync(flags, 0, nblocks * sizeof(int), stream);

    sim_kernel<<<nblocks, NTHREADS, 0, stream>>>(
        init_pos, buckle, thetas_ss, rest_len, kstiff, ksoft, kstretch,
        out, stA, stB, flags, N, H, n_coords, n_steps);
}

// Round 14
// 285.857 us; speedup vs baseline: 6.5785x; 1.3774x over previous
//
#include <hip/hip_runtime.h>

#define DT 0.001f
#define GAMMA 2.0f

#define KSTEPS 60         // steps per launch (last chunk: 40; both %4==0)
#define HALOB  120        // block halo = 2*KSTEPS (radius 2 nodes/step)
#define TILE   144        // interior nodes per block -> 228 blocks (<= 256 CUs)
#define REGION 384        // TILE + 2*HALOB = NW*WINT
#define NW     8          // waves per block (512 thr -> 2 waves/SIMD)
#define WINT   48         // wave-interior lanes (1 node each)
#define WHALO  8          // wave halo lanes per side = 2*JEXCH
#define JEXCH  4          // steps between intra-block LDS exchanges
#define NTHREADS 512

typedef float v2f __attribute__((ext_vector_type(2)));

// LDS-only barrier (global trajectory stores stay in flight).
__device__ __forceinline__ void lds_barrier() {
    asm volatile("s_waitcnt lgkmcnt(0)" ::: "memory");
    __builtin_amdgcn_s_barrier();
    asm volatile("" ::: "memory");
}

// DPP wave-wide shifts (bound_ctrl: OOB lanes get 0 -> lands only in trapezoid halo)
__device__ __forceinline__ float dpp_shl1(float x) {   // lane i <- lane i+1
    return __int_as_float(__builtin_amdgcn_update_dpp(
        0, __float_as_int(x), 0x130, 0xF, 0xF, true));
}
__device__ __forceinline__ float dpp_shr1(float x) {   // lane i <- lane i-1
    return __int_as_float(__builtin_amdgcn_update_dpp(
        0, __float_as_int(x), 0x138, 0xF, 0xF, true));
}

// Chunk kernel (17 launches). t0==0 loads initial conditions directly (init
// kernel folded in). Per-step math identical to the 298us version except the
// atan poly is Taylor-through-t^9 (err <= 2.3e-7 on |t|<0.31, libm-rounding
// level).
__global__ __launch_bounds__(NTHREADS) void chunk_kernel(
    const float* __restrict__ xin, const float* __restrict__ vin,
    float* __restrict__ xout, float* __restrict__ vout,
    const int*   __restrict__ buckle,      // (H,4) int32
    const float* __restrict__ thetas_ss,   // (H,)
    const float* __restrict__ rest_len,    // (H+1,)
    const float* __restrict__ kstiff_p,
    const float* __restrict__ ksoft_p,
    const float* __restrict__ kstretch_p,
    const float* __restrict__ init_pos,
    float* __restrict__ out,
    int N, int H, int n_coords, int t0, int ksteps, int n_steps)
{
    __shared__ float4 xch[2][REGION];      // double-buffered pos+vel exchange

    const int lane = threadIdx.x & 63;
    const int w    = threadIdx.x >> 6;
    const int r    = w * WINT + lane - WHALO;           // region node (may be OOB)
    const int tile_start = blockIdx.x * TILE;
    const int jg   = tile_start - HALOB + r;            // global node
    const bool rvalid = (r >= 0) && (r < REGION);
    const bool nvalid = (jg >= 0) && (jg < N);
    const int  jc   = min(max(jg, 0), N - 1);           // clamped load index

    const float kS  = kstiff_p[0];
    const float kw  = ksoft_p[0];
    const float kst = kstretch_p[0];

    const bool edge_ok  = (jg >= 0) && (jg <= N - 2);
    const bool hinge_ok = (jg >= 0) && (jg < H);

    // hoisted per-lane constants with validity folded in (NaN-safe)
    const float rl     = rest_len[min(max(jg, 0), H)];
    const float emask  = edge_ok ? 1.0f : 0.0f;
    const float efix   = edge_ok ? 0.0f : 1.0f;   // l2 guard: keeps rsq finite
    const float kst_l  = edge_ok ? kst : 0.0f;
    const float kstrl  = kst * rl;
    const float hfix   = hinge_ok ? 0.0f : 1.0f;  // dd guard: keeps rcp finite
    float tss = 0.0f, npf = 0.0f;
    if (hinge_ok) {
        tss = thetas_ss[jg];
        int4 bk = reinterpret_cast<const int4*>(buckle)[jg];
        npf = (float)((bk.x == 1) + (bk.y == 1) + (bk.z == 1) + (bk.w == 1));
    }
    const float ntss  = -tss;
    const float npf4m = 4.0f - npf;
    const float dKl   = hinge_ok ? (kS - kw) : 0.0f;   // K = fma(ns,dKl,kw4l)
    const float kw4l  = hinge_ok ? 4.0f * kw : 0.0f;

    const bool pinned = nvalid && (jg < 2);
    v2f pin = {0.0f, 0.0f};
    if (pinned) { pin.x = init_pos[2 * jg]; pin.y = init_pos[2 * jg + 1]; }

    const bool wave_int = (lane >= WHALO) && (lane < WHALO + WINT);
    const bool writer   = wave_int && (r >= HALOB) && (r < HALOB + TILE) && nvalid;

    v2f p, v;
    if (t0 == 0) {
        float2 P0 = reinterpret_cast<const float2*>(init_pos)[jc];
        p.x = P0.x; p.y = P0.y;
        v.x = 0.0f; v.y = 0.0f;
    } else {
        float2 P0 = reinterpret_cast<const float2*>(xin)[jc];
        float2 V0 = reinterpret_cast<const float2*>(vin)[jc];
        p.x = P0.x; p.y = P0.y;
        v.x = V0.x; v.y = V0.y;
    }

    float2* tptr = reinterpret_cast<float2*>(out + (size_t)(t0 + 1) * (size_t)n_coords) + jc;
    const size_t tstride = (size_t)(n_coords / 2);   // float2 elements per row

    const float C998 = 1.0f - GAMMA * DT;

    for (int s0 = 0; s0 < ksteps; s0 += JEXCH) {
        if (s0 > 0) {
            int buf = (s0 >> 2) & 1;
            if (wave_int && rvalid) xch[buf][r] = make_float4(p.x, p.y, v.x, v.y);
            lds_barrier();
            if (rvalid) {
                float4 f4 = xch[buf][r];
                p.x = f4.x; p.y = f4.y; v.x = f4.z; v.y = f4.w;
            }
        }
        float2 sbuf[JEXCH];                // group-local trajectory buffer (regs)
        #pragma unroll
        for (int u = 0; u < JEXCH; ++u) {
            v2f q;  q.x  = dpp_shl1(p.x); q.y  = dpp_shl1(p.y);
            v2f e  = q - p;
            v2f en; en.x = dpp_shl1(e.x); en.y = dpp_shl1(e.y);

            float l2   = fmaf(e.x, e.x, fmaf(e.y, e.y, efix));
            float irt  = __builtin_amdgcn_rsqf(l2) * emask;  // masked 1/len
            float il2  = irt * irt;
            float se   = fmaf(-kstrl, irt, kst_l);           // kst*(len-rl)/len

            float cr = e.x * en.y - e.y * en.x;
            float dd = fmaf(e.x, en.x, fmaf(e.y, en.y, hfix));
            // small-angle atan: |t| <= ~0.31; Taylor through t^9,
            // trunc err <= t^11/11 ~ 2.3e-7 (libm-rounding level)
            float t  = cr * __builtin_amdgcn_rcpf(dd);
            float t2 = t * t;
            float pp = fmaf(t2, 0.11111111f, -0.14285715f);  // t2/9 - 1/7
            pp = fmaf(t2, pp, 0.2f);
            pp = fmaf(t2, pp, -0.33333334f);
            pp = fmaf(t2, pp, 1.0f);
            float th   = pp * t;
            float thmt = th - tss;
            float ns = (th > ntss ? npf : 0.0f) + (th < tss ? npf4m : 0.0f);
            float K  = fmaf(ns, dKl, kw4l);
            float g  = K * thmt;

            float gm   = dpp_shr1(g);
            float coef = (gm - g) * il2;
            v2f F;
            F.x = fmaf(coef, -e.y, se * e.x);
            F.y = fmaf(coef,  e.x, se * e.y);
            v2f Fp; Fp.x = dpp_shr1(F.x); Fp.y = dpp_shr1(F.y);

            v2f f = F - Fp;
            v = v * C998 + f * DT;
            p = p + v * DT;
            if (tile_start == 0) {                            // uniform guard
                if (pinned) { v.x = 0.0f; v.y = 0.0f; p = pin; }
            }
            sbuf[u] = make_float2(p.x, p.y);
        }
        if (writer) {
            #pragma unroll
            for (int u = 0; u < JEXCH; ++u) {
                tptr[(size_t)u * tstride] = sbuf[u];
            }
        }
        tptr += (size_t)JEXCH * tstride;
    }

    if (writer) {
        reinterpret_cast<float2*>(xout)[jg] = make_float2(p.x, p.y);
        reinterpret_cast<float2*>(vout)[jg] = make_float2(v.x, v.y);
        if (t0 + ksteps == n_steps) {
            reinterpret_cast<float2*>(out)[jg] = make_float2(p.x, p.y);  // x_final
        }
    }
}

extern "C" void kernel_launch(void* const* d_in, const int* in_sizes, int n_in,
                              void* d_out, int out_size, void* d_ws, size_t ws_size,
                              hipStream_t stream) {
    const float* init_pos  = (const float*)d_in[0];
    const int*   buckle    = (const int*)d_in[1];
    const float* thetas_ss = (const float*)d_in[2];
    const float* rest_len  = (const float*)d_in[3];
    const float* kstiff    = (const float*)d_in[4];
    const float* ksoft     = (const float*)d_in[5];
    const float* kstretch  = (const float*)d_in[6];

    const int n_coords = in_sizes[0];             // 65540
    const int N = n_coords / 2;                   // 32770 nodes
    const int H = in_sizes[2];                    // 32768 hinges
    const int n_steps = out_size / n_coords - 1;  // 1000

    float* out = (float*)d_out;
    float* wsf = (float*)d_ws;
    float* sAx = wsf;
    float* sAv = wsf + n_coords;
    float* sBx = wsf + 2 * n_coords;
    float* sBv = wsf + 3 * n_coords;

    const int nblocks = (N + TILE - 1) / TILE;    // 228
    float* xin = sAx; float* vin = sAv;
    float* xout = sBx; float* vout = sBv;
    for (int t0 = 0; t0 < n_steps; t0 += KSTEPS) {
        int k = n_steps - t0; if (k > KSTEPS) k = KSTEPS;
        chunk_kernel<<<nblocks, NTHREADS, 0, stream>>>(
            xin, vin, xout, vout,
            buckle, thetas_ss, rest_len, kstiff, ksoft, kstretch,
            init_pos, out, N, H, n_coords, t0, k, n_steps);
        float* t1 = xin; xin = xout; xout = t1;
        float* t2 = vin; vin = vout; vout = t2;
    }
}